// Round 8
// baseline (486.346 us; speedup 1.0000x reference)
//
#include <hip/hip_runtime.h>
#include <hip/hip_bf16.h>

#define NM 50000
#define HD 128
#define KNEI 8
#define BM 64
#define SPAD 136
#define NBLK ((NM + BM - 1) / BM)   // 782
#define NH ((size_t)NM * (size_t)HD)
#define FRAG 8192                   // fragment elems per block (64 rows x 128 cols)

typedef float  fx4   __attribute__((ext_vector_type(4)));
typedef short  s16x8 __attribute__((ext_vector_type(8)));

__device__ __forceinline__ float sigm_f(float x) {
    return __builtin_amdgcn_rcpf(1.0f + __expf(-x));
}
__device__ __forceinline__ float tanh_f(float x) {
    return 2.0f * sigm_f(2.0f * x) - 1.0f;
}
__device__ __forceinline__ unsigned short f2b(float f) {
    __hip_bfloat16 h = __float2bfloat16(f);
    return __builtin_bit_cast(unsigned short, h);
}
__device__ __forceinline__ float b2f(unsigned short u) {
    __hip_bfloat16 h = __builtin_bit_cast(__hip_bfloat16, u);
    return __bfloat162float(h);
}

#define MFMA16(a, b, c) __builtin_amdgcn_mfma_f32_16x16x32_bf16(a, b, c, 0, 0, 0)

// ---- staging helpers (caller syncs) ----

__device__ __forceinline__ void stage_W16(const unsigned short* __restrict__ W16,
                                          int ldw, int woff,
                                          unsigned short (*Ws)[SPAD], int tid)
{
    const int g  = tid >> 1;
    const int c0 = (tid & 1) << 6;
    const unsigned short* src = W16 + (size_t)g * ldw + woff + c0;
    #pragma unroll
    for (int j = 0; j < 64; j += 8)
        *(s16x8*)&Ws[g][c0 + j] = *(const s16x8*)(src + j);
}

__device__ __forceinline__ void stage_A32(const float* __restrict__ A, int row0,
                                          unsigned short (*As)[SPAD], int tid)
{
    const int r  = tid & 63;
    const int c0 = (tid >> 6) << 5;
    int gr = row0 + r; if (gr >= NM) gr = NM - 1;
    const float* ap = A + (size_t)gr * HD + c0;
    #pragma unroll
    for (int j = 0; j < 32; j += 8) {
        s16x8 s;
        #pragma unroll
        for (int q = 0; q < 8; ++q) s[q] = (short)f2b(ap[j + q]);
        *(s16x8*)&As[r][c0 + j] = s;
    }
}

__device__ __forceinline__ void lds_to_g16(const unsigned short (*L)[SPAD], int row0,
                                           unsigned short* __restrict__ G, int tid)
{
    const int r  = tid & 63;
    const int c0 = (tid >> 6) << 5;
    const int gr = row0 + r;
    if (gr >= NM) return;
    #pragma unroll
    for (int j = 0; j < 32; j += 8)
        *(s16x8*)&G[(size_t)gr * HD + c0 + j] = *(const s16x8*)&L[r][c0 + j];
}

__device__ __forceinline__ void mfma_128(const unsigned short (*As)[SPAD],
                                         const unsigned short (*Ws)[SPAD],
                                         int w, int l, fx4 (&acc)[8])
{
    const int rb = w * 16 + (l & 15);
    const int kq = (l >> 4) << 3;
    #pragma unroll
    for (int ks = 0; ks < 4; ++ks) {
        const s16x8 a = *(const s16x8*)&As[rb][ks * 32 + kq];
        #pragma unroll
        for (int nf = 0; nf < 8; ++nf) {
            const s16x8 b = *(const s16x8*)&Ws[nf * 16 + (l & 15)][ks * 32 + kq];
            acc[nf] = MFMA16(a, b, acc[nf]);
        }
    }
}

#define ZACC(acc) { _Pragma("unroll") for (int z_ = 0; z_ < 8; ++z_) \
                    acc[z_] = (fx4)0.0f; }

// ---------- weight fp32 -> bf16 conversion ----------
__global__ __launch_bounds__(256)
void dgru_wcvt(const float* __restrict__ Wz, const float* __restrict__ Wr,
               const float* __restrict__ Ur, const float* __restrict__ Wh,
               unsigned short* __restrict__ w16)
{
    const int i = blockIdx.x * 256 + threadIdx.x;
    float v;
    if      (i < 32768) v = Wz[i];
    else if (i < 49152) v = Wr[i - 32768];
    else if (i < 65536) v = Ur[i - 49152];
    else                v = Wh[i - 65536];
    w16[i] = f2b(v);
}

// ---------- pre: pre_z / pre_r / pre_hf + h0 + Uh0 ----------
// pre_z / pre_hf stored in MFMA C-fragment-linear layout (padded to NBLK*FRAG).
__global__ __launch_bounds__(256)
void dgru_pre(const float* __restrict__ fmess,
              const unsigned short* __restrict__ wz16,
              const unsigned short* __restrict__ wr16,
              const unsigned short* __restrict__ wh16,
              const unsigned short* __restrict__ ur16,
              const float* __restrict__ bz, const float* __restrict__ bh,
              const float* __restrict__ bur,
              float* __restrict__ pre_z, float* __restrict__ pre_r,
              float* __restrict__ pre_hf,
              unsigned short* __restrict__ h16, unsigned short* __restrict__ uh16)
{
    __shared__ unsigned short As[BM][SPAD];
    __shared__ unsigned short Ws[HD][SPAD];
    const int tid  = threadIdx.x;
    const int row0 = blockIdx.x * BM;
    const int w    = tid >> 6;
    const int l    = tid & 63;
    const size_t fb = (size_t)blockIdx.x * FRAG + (size_t)w * 2048 + (size_t)l * 4;

    stage_A32(fmess, row0, As, tid);
    stage_W16(wz16, 2 * HD, 0, Ws, tid);
    __syncthreads();

    fx4 accz[8];
    ZACC(accz);
    mfma_128(As, Ws, w, l, accz);
    #pragma unroll
    for (int nf = 0; nf < 8; ++nf) {
        const float bv = bz[nf * 16 + (l & 15)];
        #pragma unroll
        for (int q = 0; q < 4; ++q) accz[nf][q] += bv;
        *(fx4*)&pre_z[fb + nf * 256] = accz[nf];
    }
    __syncthreads();

    stage_W16(wr16, HD, 0, Ws, tid);
    __syncthreads();
    {
        fx4 acc[8]; ZACC(acc);
        mfma_128(As, Ws, w, l, acc);
        #pragma unroll
        for (int nf = 0; nf < 8; ++nf) {
            const int col = nf * 16 + (l & 15);
            #pragma unroll
            for (int q = 0; q < 4; ++q) {
                const int gr = row0 + w * 16 + ((l >> 4) << 2) + q;
                if (gr < NM) pre_r[(size_t)gr * HD + col] = acc[nf][q];
            }
        }
    }
    __syncthreads();

    stage_W16(wh16, 2 * HD, 0, Ws, tid);
    __syncthreads();
    {
        fx4 acc[8]; ZACC(acc);
        mfma_128(As, Ws, w, l, acc);
        __syncthreads();   // all waves done reading As before h0 overwrite
        #pragma unroll
        for (int nf = 0; nf < 8; ++nf) {
            const int col = nf * 16 + (l & 15);
            const float bv = bh[nf * 16 + (l & 15)];
            fx4 p;
            #pragma unroll
            for (int q = 0; q < 4; ++q) p[q] = acc[nf][q] + bv;
            *(fx4*)&pre_hf[fb + nf * 256] = p;
            #pragma unroll
            for (int q = 0; q < 4; ++q) {
                const int rl = w * 16 + ((l >> 4) << 2) + q;
                const int gr = row0 + rl;
                float h0 = sigm_f(accz[nf][q]) * tanh_f(p[q]);
                if (gr == 0) h0 = 0.0f;
                As[rl][col] = f2b(h0);
            }
        }
    }
    stage_W16(ur16, HD, 0, Ws, tid);
    __syncthreads();

    lds_to_g16(As, row0, h16, tid);
    {
        fx4 acc[8]; ZACC(acc);
        mfma_128(As, Ws, w, l, acc);
        __syncthreads();   // Ws readers done before Uh overwrite
        #pragma unroll
        for (int nf = 0; nf < 8; ++nf) {
            const int col = nf * 16 + (l & 15);
            const float bv = bur[nf * 16 + (l & 15)];
            #pragma unroll
            for (int q = 0; q < 4; ++q) {
                const int rl = w * 16 + ((l >> 4) << 2) + q;
                Ws[rl][col] = f2b(acc[nf][q] + bv);
            }
        }
        __syncthreads();
        lds_to_g16(Ws, row0, uh16, tid);
    }
}

// ---------- iter: fused gather + z-GEMM + h-GEMM/GRU + Uh-GEMM ----------
// Reads h16r/uh16r (iteration t), writes h16w/uh16w (iteration t+1).
// Ping-pong buffers => no cross-block read/write race within a launch.
__global__ __launch_bounds__(256)
void dgru_iter(const int* __restrict__ bgraph, const float* __restrict__ pre_r,
               const float* __restrict__ pre_z, const float* __restrict__ pre_hf,
               const unsigned short* __restrict__ wz16,
               const unsigned short* __restrict__ wh16,
               const unsigned short* __restrict__ ur16,
               const float* __restrict__ bur,
               const unsigned short* __restrict__ h16r,
               const unsigned short* __restrict__ uh16r,
               unsigned short* __restrict__ h16w,
               unsigned short* __restrict__ uh16w,
               float* __restrict__ hout, int last)
{
    __shared__ unsigned short AsH[BM][SPAD];   // sum_h tile, then new h
    __shared__ unsigned short AsG[BM][SPAD];   // sum_gated tile, then new Uh
    __shared__ unsigned short Ws[HD][SPAD];
    const int tid  = threadIdx.x;
    const int row0 = blockIdx.x * BM;
    const int w    = tid >> 6;
    const int l    = tid & 63;
    const size_t fb = (size_t)blockIdx.x * FRAG + (size_t)w * 2048 + (size_t)l * 4;

    stage_W16(wz16, 2 * HD, HD, Ws, tid);      // Wz2 while gathering

    // ---- gather phase: 4 threads/msg, 32 dims each ----
    {
        const int r  = tid >> 2;
        const int c0 = (tid & 3) << 5;
        int n = row0 + r; if (n >= NM) n = NM - 1;

        const int4* bg = (const int4*)(bgraph + (size_t)n * KNEI);
        const int4 bA = bg[0], bB = bg[1];
        const int idx[KNEI] = {bA.x, bA.y, bA.z, bA.w, bB.x, bB.y, bB.z, bB.w};

        float prv[32];
        {
            const float* prp = pre_r + (size_t)n * HD + c0;
            #pragma unroll
            for (int j = 0; j < 32; j += 4) *(fx4*)&prv[j] = *(const fx4*)(prp + j);
        }
        float sh[32], sg[32];
        #pragma unroll
        for (int j = 0; j < 32; ++j) { sh[j] = 0.0f; sg[j] = 0.0f; }

        #pragma unroll
        for (int k = 0; k < KNEI; ++k) {
            const unsigned short* hp = h16r  + (size_t)idx[k] * HD + c0;
            const unsigned short* up = uh16r + (size_t)idx[k] * HD + c0;
            s16x8 hb[4], ub[4];
            #pragma unroll
            for (int j4 = 0; j4 < 4; ++j4) hb[j4] = *(const s16x8*)(hp + j4 * 8);
            #pragma unroll
            for (int j4 = 0; j4 < 4; ++j4) ub[j4] = *(const s16x8*)(up + j4 * 8);
            #pragma unroll
            for (int j = 0; j < 32; ++j) {
                const float hv = b2f((unsigned short)hb[j >> 3][j & 7]);
                const float uv = b2f((unsigned short)ub[j >> 3][j & 7]);
                sh[j] += hv;
                sg[j] = fmaf(sigm_f(prv[j] + uv), hv, sg[j]);
            }
        }
        #pragma unroll
        for (int j = 0; j < 32; j += 8) {
            s16x8 a, g;
            #pragma unroll
            for (int q = 0; q < 8; ++q) {
                a[q] = (short)f2b(sh[j + q]);
                g[q] = (short)f2b(sg[j + q]);
            }
            *(s16x8*)&AsH[r][c0 + j] = a;
            *(s16x8*)&AsG[r][c0 + j] = g;
        }
    }
    __syncthreads();                           // S1: tiles + Wz2 ready

    // ---- z-GEMM: z = sigmoid(pre_z + sum_h @ Wz2.T), registers only ----
    fx4 zres[8];
    {
        fx4 acc[8]; ZACC(acc);
        mfma_128(AsH, Ws, w, l, acc);
        #pragma unroll
        for (int nf = 0; nf < 8; ++nf) {
            const fx4 p = *(const fx4*)&pre_z[fb + nf * 256];
            #pragma unroll
            for (int q = 0; q < 4; ++q) zres[nf][q] = sigm_f(p[q] + acc[nf][q]);
        }
    }
    __syncthreads();                           // S2: Ws readers done

    stage_W16(wh16, 2 * HD, HD, Ws, tid);
    __syncthreads();                           // S3

    // ---- h-GEMM: ph = tanh(pre_hf + sum_g @ Wh2.T); h = (1-z)*sum_h + z*ph ----
    {
        fx4 acc[8]; ZACC(acc);
        mfma_128(AsG, Ws, w, l, acc);
        #pragma unroll
        for (int nf = 0; nf < 8; ++nf) {
            const int col = nf * 16 + (l & 15);
            const fx4 p = *(const fx4*)&pre_hf[fb + nf * 256];
            #pragma unroll
            for (int q = 0; q < 4; ++q) {
                const int rl = w * 16 + ((l >> 4) << 2) + q;
                const int gr = row0 + rl;
                const float shv = b2f(AsH[rl][col]);
                const float zz  = zres[nf][q];
                float o = (1.0f - zz) * shv + zz * tanh_f(p[q] + acc[nf][q]);
                if (gr == 0) o = 0.0f;
                if (last) {
                    if (gr < NM) hout[(size_t)gr * HD + col] = o;
                } else {
                    AsH[rl][col] = f2b(o);     // own element: read+write by owner only
                }
            }
        }
    }
    if (last) return;
    __syncthreads();                           // S4: new-h writes + Ws readers done

    stage_W16(ur16, HD, 0, Ws, tid);
    lds_to_g16(AsH, row0, h16w, tid);
    __syncthreads();                           // S5

    // ---- Uh-GEMM: Uh = h @ Ur.T + bur ----
    {
        fx4 acc[8]; ZACC(acc);
        mfma_128(AsH, Ws, w, l, acc);
        __syncthreads();                       // order before AsG overwrite
        #pragma unroll
        for (int nf = 0; nf < 8; ++nf) {
            const int col = nf * 16 + (l & 15);
            const float bv = bur[nf * 16 + (l & 15)];
            #pragma unroll
            for (int q = 0; q < 4; ++q) {
                const int rl = w * 16 + ((l >> 4) << 2) + q;
                AsG[rl][col] = f2b(acc[nf][q] + bv);
            }
        }
        __syncthreads();                       // S6
        lds_to_g16(AsG, row0, uh16w, tid);
    }
}

extern "C" void kernel_launch(void* const* d_in, const int* in_sizes, int n_in,
                              void* d_out, int out_size, void* d_ws, size_t ws_size,
                              hipStream_t stream) {
    const float* fmess  = (const float*)d_in[0];
    const int*   bgraph = (const int*)  d_in[1];
    const float* W_z    = (const float*)d_in[2];
    const float* b_z    = (const float*)d_in[3];
    const float* W_r    = (const float*)d_in[4];
    const float* U_r    = (const float*)d_in[5];
    const float* b_Ur   = (const float*)d_in[6];
    const float* W_h    = (const float*)d_in[7];
    const float* b_h    = (const float*)d_in[8];

    float* ws = (float*)d_ws;
    const size_t FPAD = (size_t)NBLK * FRAG;   // 6406144 elems
    float* pre_z  = ws;                        // fragment layout
    float* pre_hf = ws + FPAD;                 // fragment layout
    float* pre_r  = ws + 2 * FPAD;             // row-major
    unsigned short* h16a  = (unsigned short*)(pre_r + NH);   // ping-pong pair A
    unsigned short* uh16a = h16a + NH;
    unsigned short* h16b  = uh16a + NH;                      // ping-pong pair B
    unsigned short* uh16b = h16b + NH;
    unsigned short* w16   = uh16b + NH;
    unsigned short* wz16 = w16;                // [128][256]
    unsigned short* wr16 = w16 + 32768;        // [128][128]
    unsigned short* ur16 = w16 + 49152;        // [128][128]
    unsigned short* wh16 = w16 + 65536;        // [128][256]
    float* hout = (float*)d_out;
    // ws usage ~= 141 MB (R2/R3 used 153.6 OK)

    dgru_wcvt<<<dim3(384), dim3(256), 0, stream>>>(W_z, W_r, U_r, W_h, w16);

    dgru_pre<<<dim3(NBLK), dim3(256), 0, stream>>>(
        fmess, wz16, wr16, wh16, ur16, b_z, b_h, b_Ur,
        pre_z, pre_r, pre_hf, h16a, uh16a);

    for (int it = 1; it < 5; ++it) {
        const int pa = (it & 1);               // it odd: read A write B; even: read B write A
        const unsigned short* hr = pa ? h16a : h16b;
        const unsigned short* ur = pa ? uh16a : uh16b;
        unsigned short* hw = pa ? h16b : h16a;
        unsigned short* uw = pa ? uh16b : uh16a;
        dgru_iter<<<dim3(NBLK), dim3(256), 0, stream>>>(
            bgraph, pre_r, pre_z, pre_hf, wz16, wh16, ur16, b_Ur,
            hr, ur, hw, uw, hout, (it == 4) ? 1 : 0);
    }
}

// Round 9
// 330.098 us; speedup vs baseline: 1.4733x; 1.4733x over previous
//
#include <hip/hip_runtime.h>
#include <hip/hip_bf16.h>

#define NM 50000
#define HD 128
#define KNEI 8
#define BM 64
#define SPAD 136
#define NBLK ((NM + BM - 1) / BM)   // 782
#define NH ((size_t)NM * (size_t)HD)
#define FRAG 8192                   // fragment elems per block (64 rows x 128 cols)

typedef float  fx4   __attribute__((ext_vector_type(4)));
typedef short  s16x8 __attribute__((ext_vector_type(8)));
typedef short  s16x4 __attribute__((ext_vector_type(4)));

__device__ __forceinline__ float sigm_f(float x) {
    return __builtin_amdgcn_rcpf(1.0f + __expf(-x));
}
__device__ __forceinline__ float tanh_f(float x) {
    return 2.0f * sigm_f(2.0f * x) - 1.0f;
}
__device__ __forceinline__ unsigned short f2b(float f) {
    __hip_bfloat16 h = __float2bfloat16(f);
    return __builtin_bit_cast(unsigned short, h);
}
__device__ __forceinline__ float b2f(unsigned short u) {
    __hip_bfloat16 h = __builtin_bit_cast(__hip_bfloat16, u);
    return __bfloat162float(h);
}

#define MFMA16(a, b, c) __builtin_amdgcn_mfma_f32_16x16x32_bf16(a, b, c, 0, 0, 0)

// ---- staging helpers (caller syncs) ----

__device__ __forceinline__ void stage_W16(const unsigned short* __restrict__ W16,
                                          int ldw, int woff,
                                          unsigned short (*Ws)[SPAD], int tid)
{
    const int g  = tid >> 1;
    const int c0 = (tid & 1) << 6;
    const unsigned short* src = W16 + (size_t)g * ldw + woff + c0;
    #pragma unroll
    for (int j = 0; j < 64; j += 8)
        *(s16x8*)&Ws[g][c0 + j] = *(const s16x8*)(src + j);
}

__device__ __forceinline__ void stage_A32(const float* __restrict__ A, int row0,
                                          unsigned short (*As)[SPAD], int tid)
{
    const int r  = tid & 63;
    const int c0 = (tid >> 6) << 5;
    int gr = row0 + r; if (gr >= NM) gr = NM - 1;
    const float* ap = A + (size_t)gr * HD + c0;
    #pragma unroll
    for (int j = 0; j < 32; j += 8) {
        s16x8 s;
        #pragma unroll
        for (int q = 0; q < 8; ++q) s[q] = (short)f2b(ap[j + q]);
        *(s16x8*)&As[r][c0 + j] = s;
    }
}

__device__ __forceinline__ void stage_A16(const unsigned short* __restrict__ A16, int row0,
                                          unsigned short (*As)[SPAD], int tid)
{
    const int r  = tid & 63;
    const int c0 = (tid >> 6) << 5;
    int gr = row0 + r; if (gr >= NM) gr = NM - 1;
    const unsigned short* ap = A16 + (size_t)gr * HD + c0;
    #pragma unroll
    for (int j = 0; j < 32; j += 8)
        *(s16x8*)&As[r][c0 + j] = *(const s16x8*)(ap + j);
}

__device__ __forceinline__ void lds_to_g16(const unsigned short (*L)[SPAD], int row0,
                                           unsigned short* __restrict__ G, int tid)
{
    const int r  = tid & 63;
    const int c0 = (tid >> 6) << 5;
    const int gr = row0 + r;
    if (gr >= NM) return;
    #pragma unroll
    for (int j = 0; j < 32; j += 8)
        *(s16x8*)&G[(size_t)gr * HD + c0 + j] = *(const s16x8*)&L[r][c0 + j];
}

__device__ __forceinline__ void mfma_128(const unsigned short (*As)[SPAD],
                                         const unsigned short (*Ws)[SPAD],
                                         int w, int l, fx4 (&acc)[8])
{
    const int rb = w * 16 + (l & 15);
    const int kq = (l >> 4) << 3;
    #pragma unroll
    for (int ks = 0; ks < 4; ++ks) {
        const s16x8 a = *(const s16x8*)&As[rb][ks * 32 + kq];
        #pragma unroll
        for (int nf = 0; nf < 8; ++nf) {
            const s16x8 b = *(const s16x8*)&Ws[nf * 16 + (l & 15)][ks * 32 + kq];
            acc[nf] = MFMA16(a, b, acc[nf]);
        }
    }
}

#define ZACC(acc) { _Pragma("unroll") for (int z_ = 0; z_ < 8; ++z_) \
                    acc[z_] = (fx4)0.0f; }

// ---------- weight fp32 -> bf16 conversion ----------
__global__ __launch_bounds__(256)
void dgru_wcvt(const float* __restrict__ Wz, const float* __restrict__ Wr,
               const float* __restrict__ Ur, const float* __restrict__ Wh,
               unsigned short* __restrict__ w16)
{
    const int i = blockIdx.x * 256 + threadIdx.x;
    float v;
    if      (i < 32768) v = Wz[i];
    else if (i < 49152) v = Wr[i - 32768];
    else if (i < 65536) v = Ur[i - 49152];
    else                v = Wh[i - 65536];
    w16[i] = f2b(v);
}

// ---------- pre: pre_z / pre_r / pre_hf + h0 + Uh0 ----------
// pre_z / pre_hf stored in MFMA C-fragment-linear layout (padded to NBLK*FRAG).
__global__ __launch_bounds__(256)
void dgru_pre(const float* __restrict__ fmess,
              const unsigned short* __restrict__ wz16,
              const unsigned short* __restrict__ wr16,
              const unsigned short* __restrict__ wh16,
              const unsigned short* __restrict__ ur16,
              const float* __restrict__ bz, const float* __restrict__ bh,
              const float* __restrict__ bur,
              float* __restrict__ pre_z, float* __restrict__ pre_r,
              float* __restrict__ pre_hf,
              unsigned short* __restrict__ h16, unsigned short* __restrict__ uh16)
{
    __shared__ unsigned short As[BM][SPAD];
    __shared__ unsigned short Ws[HD][SPAD];
    const int tid  = threadIdx.x;
    const int row0 = blockIdx.x * BM;
    const int w    = tid >> 6;
    const int l    = tid & 63;
    const size_t fb = (size_t)blockIdx.x * FRAG + (size_t)w * 2048 + (size_t)l * 4;

    stage_A32(fmess, row0, As, tid);
    stage_W16(wz16, 2 * HD, 0, Ws, tid);
    __syncthreads();

    fx4 accz[8];
    ZACC(accz);
    mfma_128(As, Ws, w, l, accz);
    #pragma unroll
    for (int nf = 0; nf < 8; ++nf) {
        const float bv = bz[nf * 16 + (l & 15)];
        #pragma unroll
        for (int q = 0; q < 4; ++q) accz[nf][q] += bv;
        *(fx4*)&pre_z[fb + nf * 256] = accz[nf];
    }
    __syncthreads();

    stage_W16(wr16, HD, 0, Ws, tid);
    __syncthreads();
    {
        fx4 acc[8]; ZACC(acc);
        mfma_128(As, Ws, w, l, acc);
        #pragma unroll
        for (int nf = 0; nf < 8; ++nf) {
            const int col = nf * 16 + (l & 15);
            #pragma unroll
            for (int q = 0; q < 4; ++q) {
                const int gr = row0 + w * 16 + ((l >> 4) << 2) + q;
                if (gr < NM) pre_r[(size_t)gr * HD + col] = acc[nf][q];
            }
        }
    }
    __syncthreads();

    stage_W16(wh16, 2 * HD, 0, Ws, tid);
    __syncthreads();
    {
        fx4 acc[8]; ZACC(acc);
        mfma_128(As, Ws, w, l, acc);
        __syncthreads();   // all waves done reading As before h0 overwrite
        #pragma unroll
        for (int nf = 0; nf < 8; ++nf) {
            const int col = nf * 16 + (l & 15);
            const float bv = bh[nf * 16 + (l & 15)];
            fx4 p;
            #pragma unroll
            for (int q = 0; q < 4; ++q) p[q] = acc[nf][q] + bv;
            *(fx4*)&pre_hf[fb + nf * 256] = p;
            #pragma unroll
            for (int q = 0; q < 4; ++q) {
                const int rl = w * 16 + ((l >> 4) << 2) + q;
                const int gr = row0 + rl;
                float h0 = sigm_f(accz[nf][q]) * tanh_f(p[q]);
                if (gr == 0) h0 = 0.0f;
                As[rl][col] = f2b(h0);
            }
        }
    }
    stage_W16(ur16, HD, 0, Ws, tid);
    __syncthreads();

    lds_to_g16(As, row0, h16, tid);
    {
        fx4 acc[8]; ZACC(acc);
        mfma_128(As, Ws, w, l, acc);
        __syncthreads();   // Ws readers done before Uh overwrite
        #pragma unroll
        for (int nf = 0; nf < 8; ++nf) {
            const int col = nf * 16 + (l & 15);
            const float bv = bur[nf * 16 + (l & 15)];
            #pragma unroll
            for (int q = 0; q < 4; ++q) {
                const int rl = w * 16 + ((l >> 4) << 2) + q;
                Ws[rl][col] = f2b(acc[nf][q] + bv);
            }
        }
        __syncthreads();
        lds_to_g16(Ws, row0, uh16, tid);
    }
}

// ---------- gather (standalone, high occupancy): bf16 in, bf16 sums out ----------
__global__ __launch_bounds__(256)
void dgru_gather(const unsigned short* __restrict__ h16,
                 const unsigned short* __restrict__ uh16,
                 const int* __restrict__ bgraph, const float* __restrict__ pre_r,
                 unsigned short* __restrict__ sh16, unsigned short* __restrict__ sg16)
{
    const int tid = threadIdx.x;
    const int n   = blockIdx.x * 8 + (tid >> 5);   // grid covers NM exactly
    const int d0  = (tid & 31) << 2;

    const int4* bg = (const int4*)(bgraph + (size_t)n * KNEI);
    const int4 b0 = bg[0], b1 = bg[1];
    const int idx[KNEI] = {b0.x, b0.y, b0.z, b0.w, b1.x, b1.y, b1.z, b1.w};

    s16x4 hr[KNEI], ur[KNEI];
    #pragma unroll
    for (int k = 0; k < KNEI; ++k)
        hr[k] = *(const s16x4*)&h16[(size_t)idx[k] * HD + d0];
    #pragma unroll
    for (int k = 0; k < KNEI; ++k)
        ur[k] = *(const s16x4*)&uh16[(size_t)idx[k] * HD + d0];
    const fx4 pr = *(const fx4*)&pre_r[(size_t)n * HD + d0];

    float sh[4] = {0.f, 0.f, 0.f, 0.f};
    float sg[4] = {0.f, 0.f, 0.f, 0.f};
    #pragma unroll
    for (int k = 0; k < KNEI; ++k) {
        #pragma unroll
        for (int j = 0; j < 4; ++j) {
            const float hv = b2f((unsigned short)hr[k][j]);
            const float uv = b2f((unsigned short)ur[k][j]);
            sh[j] += hv;
            sg[j] = fmaf(sigm_f(pr[j] + uv), hv, sg[j]);
        }
    }
    s16x4 osh, osg;
    #pragma unroll
    for (int j = 0; j < 4; ++j) {
        osh[j] = (short)f2b(sh[j]);
        osg[j] = (short)f2b(sg[j]);
    }
    const size_t o = (size_t)n * HD + d0;
    *(s16x4*)&sh16[o] = osh;
    *(s16x4*)&sg16[o] = osg;
}

// ---------- zh: z-GEMM (z in regs) + h-GEMM/GRU update + next Uh ----------
// pre_z / pre_hf read in fragment layout (coalesced fx4); sum_h re-read from LDS.
__global__ __launch_bounds__(256)
void dgru_zh(const unsigned short* __restrict__ sh16,
             const unsigned short* __restrict__ sg16,
             const float* __restrict__ pre_z, const float* __restrict__ pre_hf,
             const unsigned short* __restrict__ wz16,
             const unsigned short* __restrict__ wh16,
             const unsigned short* __restrict__ ur16,
             const float* __restrict__ bur,
             unsigned short* __restrict__ h16, unsigned short* __restrict__ uh16,
             float* __restrict__ hout, int last)
{
    __shared__ unsigned short AsH[BM][SPAD];   // sum_h tile, then new h
    __shared__ unsigned short AsG[BM][SPAD];   // sum_gated tile, then new Uh
    __shared__ unsigned short Ws[HD][SPAD];
    const int tid  = threadIdx.x;
    const int row0 = blockIdx.x * BM;
    const int w    = tid >> 6;
    const int l    = tid & 63;
    const size_t fb = (size_t)blockIdx.x * FRAG + (size_t)w * 2048 + (size_t)l * 4;

    // ---- phase 1: z = sigmoid(pre_z + sum_h @ Wz2.T), registers only ----
    stage_A16(sh16, row0, AsH, tid);
    stage_A16(sg16, row0, AsG, tid);
    stage_W16(wz16, 2 * HD, HD, Ws, tid);
    __syncthreads();                           // S1
    fx4 zres[8];
    {
        fx4 acc[8]; ZACC(acc);
        mfma_128(AsH, Ws, w, l, acc);
        #pragma unroll
        for (int nf = 0; nf < 8; ++nf) {
            const fx4 p = *(const fx4*)&pre_z[fb + nf * 256];
            #pragma unroll
            for (int q = 0; q < 4; ++q) zres[nf][q] = sigm_f(p[q] + acc[nf][q]);
        }
    }
    __syncthreads();                           // S2: Ws readers done

    stage_W16(wh16, 2 * HD, HD, Ws, tid);
    __syncthreads();                           // S3

    // ---- phase 2: ph = tanh(pre_hf + sum_g @ Wh2.T); h = (1-z)*sum_h + z*ph ----
    {
        fx4 acc[8]; ZACC(acc);
        mfma_128(AsG, Ws, w, l, acc);
        #pragma unroll
        for (int nf = 0; nf < 8; ++nf) {
            const int col = nf * 16 + (l & 15);
            const fx4 p = *(const fx4*)&pre_hf[fb + nf * 256];
            #pragma unroll
            for (int q = 0; q < 4; ++q) {
                const int rl = w * 16 + ((l >> 4) << 2) + q;
                const int gr = row0 + rl;
                const float shv = b2f(AsH[rl][col]);   // sum_h from LDS
                const float zz  = zres[nf][q];
                float o = (1.0f - zz) * shv + zz * tanh_f(p[q] + acc[nf][q]);
                if (gr == 0) o = 0.0f;
                if (last) {
                    if (gr < NM) hout[(size_t)gr * HD + col] = o;
                } else {
                    AsH[rl][col] = f2b(o);     // owner-only element, no race
                }
            }
        }
    }
    if (last) return;
    __syncthreads();                           // S4: h updates visible; Ws readers done

    stage_W16(ur16, HD, 0, Ws, tid);
    lds_to_g16(AsH, row0, h16, tid);
    __syncthreads();                           // S5

    // ---- phase 3: Uh = h @ Ur.T + bur ----
    {
        fx4 acc[8]; ZACC(acc);
        mfma_128(AsH, Ws, w, l, acc);
        __syncthreads();                       // order before AsG overwrite
        #pragma unroll
        for (int nf = 0; nf < 8; ++nf) {
            const int col = nf * 16 + (l & 15);
            const float bv = bur[nf * 16 + (l & 15)];
            #pragma unroll
            for (int q = 0; q < 4; ++q) {
                const int rl = w * 16 + ((l >> 4) << 2) + q;
                AsG[rl][col] = f2b(acc[nf][q] + bv);
            }
        }
        __syncthreads();                       // S6
        lds_to_g16(AsG, row0, uh16, tid);
    }
}

extern "C" void kernel_launch(void* const* d_in, const int* in_sizes, int n_in,
                              void* d_out, int out_size, void* d_ws, size_t ws_size,
                              hipStream_t stream) {
    const float* fmess  = (const float*)d_in[0];
    const int*   bgraph = (const int*)  d_in[1];
    const float* W_z    = (const float*)d_in[2];
    const float* b_z    = (const float*)d_in[3];
    const float* W_r    = (const float*)d_in[4];
    const float* U_r    = (const float*)d_in[5];
    const float* b_Ur   = (const float*)d_in[6];
    const float* W_h    = (const float*)d_in[7];
    const float* b_h    = (const float*)d_in[8];

    float* ws = (float*)d_ws;
    const size_t FPAD = (size_t)NBLK * FRAG;   // 6406144 elems
    float* pre_z  = ws;                        // fragment layout
    float* pre_hf = ws + FPAD;                 // fragment layout
    float* pre_r  = ws + 2 * FPAD;             // row-major
    unsigned short* h16  = (unsigned short*)(pre_r + NH);
    unsigned short* uh16 = h16 + NH;
    unsigned short* sh16 = uh16 + NH;
    unsigned short* sg16 = sh16 + NH;
    unsigned short* w16  = sg16 + NH;
    unsigned short* wz16 = w16;                // [128][256]
    unsigned short* wr16 = w16 + 32768;        // [128][128]
    unsigned short* ur16 = w16 + 49152;        // [128][128]
    unsigned short* wh16 = w16 + 65536;        // [128][256]
    float* hout = (float*)d_out;
    // ws usage ~= 128 MB (prior rounds used up to 153.6, OK)

    dgru_wcvt<<<dim3(384), dim3(256), 0, stream>>>(W_z, W_r, U_r, W_h, w16);

    dgru_pre<<<dim3(NBLK), dim3(256), 0, stream>>>(
        fmess, wz16, wr16, wh16, ur16, b_z, b_h, b_Ur,
        pre_z, pre_r, pre_hf, h16, uh16);

    for (int it = 1; it < 5; ++it) {
        dgru_gather<<<dim3(NM / 8), dim3(256), 0, stream>>>(
            h16, uh16, bgraph, pre_r, sh16, sg16);
        dgru_zh<<<dim3(NBLK), dim3(256), 0, stream>>>(
            sh16, sg16, pre_z, pre_hf, wz16, wh16, ur16, b_Ur,
            h16, uh16, hout, (it == 4) ? 1 : 0);
    }
}